// Round 13
// baseline (536.810 us; speedup 1.0000x reference)
//
#include <hip/hip_runtime.h>
#include <stdint.h>

typedef unsigned short u16;
typedef unsigned int   u32;

#define DEVINL __device__ __forceinline__

typedef __bf16 bf16x8 __attribute__((ext_vector_type(8)));
typedef float  f32x4  __attribute__((ext_vector_type(4)));
typedef unsigned short u16x8 __attribute__((ext_vector_type(8)));

#define RSQRT512 0.044194173824159216f
#define LRELU_G  1.4142135623730951f

DEVINL u16 f2bf(float f) {           // RNE float->bf16 bits
  union { float f; u32 u; } v; v.f = f;
  u32 r = v.u + 0x7fffu + ((v.u >> 16) & 1u);
  return (u16)(r >> 16);
}
DEVINL float bf2f(u16 b) {
  union { u32 u; float f; } v; v.u = ((u32)b) << 16;
  return v.f;
}

#define AS1 __attribute__((address_space(1)))
#define AS3 __attribute__((address_space(3)))
// async global->LDS, 16B per lane; LDS dest = wave-uniform base + lane*16
DEVINL void gload16(const void* g, void* l) {
  __builtin_amdgcn_global_load_lds((AS1 const u32*)(uintptr_t)g,
                                   (AS3 u32*)(u32)(uintptr_t)l, 16, 0, 0);
}

// ---------------------------------------------------------------------------
// 1) styles
// ---------------------------------------------------------------------------
__global__ __launch_bounds__(256)
void style_kernel(const float* __restrict__ wsin,
                  const float* __restrict__ a0w, const float* __restrict__ a0b,
                  const float* __restrict__ a1w, const float* __restrict__ a1b,
                  const float* __restrict__ atw, const float* __restrict__ atb,
                  float* __restrict__ s_all)
{
  int wid = threadIdx.x >> 6, lane = threadIdx.x & 63;
  int idx = blockIdx.x * 4 + wid;            // [0, 3*8*512)
  int j = idx >> 12;
  int b = (idx >> 9) & 7;
  int o = idx & 511;
  const float* A  = (j == 0) ? a0w : ((j == 1) ? a1w : atw);
  const float* Ab = (j == 0) ? a0b : ((j == 1) ? a1b : atb);
  const float* wv = wsin + (b * 3 + j) * 512;
  float p = 0.f;
  #pragma unroll
  for (int m = 0; m < 512; m += 64) p += wv[m + lane] * A[(size_t)o * 512 + m + lane];
  #pragma unroll
  for (int s = 32; s; s >>= 1) p += __shfl_xor(p, s, 64);
  if (lane == 0) {
    float v = p * RSQRT512 + Ab[o];
    if (j == 2) v *= RSQRT512;
    s_all[idx] = v;
  }
}

// ---------------------------------------------------------------------------
// 2a) demod: d[b][o] = rsqrt(sum_{i,k} (w*s)^2 + 1e-8)  (same numerics as old wprep)
// ---------------------------------------------------------------------------
__global__ __launch_bounds__(256)
void demod_kernel(const float* __restrict__ w, const float* __restrict__ s_j,
                  float* __restrict__ dOut)
{
  int b = blockIdx.x >> 9;
  int o = blockIdx.x & 511;
  __shared__ float s_sh[512];
  __shared__ float red[4];
  int t = threadIdx.x;
  s_sh[t]       = s_j[b * 512 + t];
  s_sh[t + 256] = s_j[b * 512 + t + 256];
  __syncthreads();
  float ssq = 0.f;
  #pragma unroll
  for (int hh = 0; hh < 2; ++hh) {
    int i = t + hh * 256;
    float si = s_sh[i];
    const float* wp = w + ((size_t)o * 512 + i) * 9;
    #pragma unroll
    for (int k = 0; k < 9; ++k) { float v = wp[k] * si; ssq += v * v; }
  }
  #pragma unroll
  for (int s = 32; s; s >>= 1) ssq += __shfl_xor(ssq, s, 64);
  if ((t & 63) == 0) red[t >> 6] = ssq;
  __syncthreads();
  if (t == 0) {
    float d = red[0] + red[1] + red[2] + red[3];
    dOut[b * 512 + o] = 1.0f / sqrtf(d + 1e-8f);
  }
}

// ---------------------------------------------------------------------------
// 2b) wpack: emit wg2[b][tapOut][kq][o][8] bf16, COALESCED writes (1KB/wave).
//    block=(b,kq); thread reads its o's 72 consecutive floats (8ch x 9taps).
//    FLIP: source tap ksrc = 8 - tapOut  (since (2-ky)*3+(2-kx) = 8-(ky*3+kx))
// ---------------------------------------------------------------------------
template <int FLIP>
__global__ __launch_bounds__(256)
void wpack_kernel(const float* __restrict__ w, const float* __restrict__ s_j,
                  const float* __restrict__ dIn, u16* __restrict__ wg)
{
  int b = blockIdx.x >> 6;
  int kq = blockIdx.x & 63;
  float sv[8];
  #pragma unroll
  for (int e = 0; e < 8; ++e) sv[e] = s_j[b * 512 + kq * 8 + e];
  int t = threadIdx.x;
  #pragma unroll 1
  for (int rep = 0; rep < 2; ++rep) {
    int o = rep * 256 + t;
    float d = dIn[b * 512 + o];
    const float* wp = w + ((size_t)o * 512 + kq * 8) * 9;   // 72 consecutive f32
    float wv[72];
    #pragma unroll
    for (int j = 0; j < 72; ++j) wv[j] = wp[j];
    #pragma unroll
    for (int tapOut = 0; tapOut < 9; ++tapOut) {
      int ksrc = FLIP ? (8 - tapOut) : tapOut;
      u16x8 g;
      #pragma unroll
      for (int e = 0; e < 8; ++e) g[e] = f2bf(wv[e * 9 + ksrc] * sv[e] * d);
      *(u16x8*)&wg[((((size_t)(b * 9 + tapOut)) * 64 + kq) * 512 + o) * 8] = g;
    }
  }
}

// ---------------------------------------------------------------------------
// 3) x (NCHW f32 32x32) -> xt (NHWC f32) via LDS transpose
// ---------------------------------------------------------------------------
__global__ __launch_bounds__(256)
void transpose_x(const float* __restrict__ x, float* __restrict__ xt)
{
  int b = blockIdx.x >> 5, y = blockIdx.x & 31;
  __shared__ __align__(16) float lds[32][260];
  int t = threadIdx.x;
  #pragma unroll 1
  for (int half = 0; half < 2; ++half) {
    for (int idx = t; idx < 8192; idx += 256) {
      int xq = idx & 31, i = idx >> 5;
      lds[xq][i] = x[(((size_t)(b * 512 + half * 256 + i)) << 10) + (y << 5) + xq];
    }
    __syncthreads();
    for (int idx = t; idx < 2048; idx += 256) {
      int xq = idx >> 6, i4 = idx & 63;
      float4 v = *(const float4*)&lds[xq][i4 * 4];
      *(float4*)&xt[((size_t)((b * 32 + y) * 32 + xq) << 9) + half * 256 + i4 * 4] = v;
    }
    __syncthreads();
  }
}

// ---------------------------------------------------------------------------
// 4) blur-upsample -> xb2 K-planar [b][c8][66][66][8], COALESCED writes.
//    block=(b,c8); thread=(x = idx>>3, e = idx&7); loop y rows.
// ---------------------------------------------------------------------------
__global__ __launch_bounds__(256)
void upblur_kernel(const float* __restrict__ xt, u16* __restrict__ xb)
{
  int b = blockIdx.x >> 6, c8 = blockIdx.x & 63;
  const float* base = xt + (size_t)b * 524288 + c8 * 8;   // + (m*32+n)*512 + e
  u16* ob = xb + ((size_t)(b * 64 + c8)) * 34848;         // 66*66*8
  int t = threadIdx.x;
  #pragma unroll 1
  for (int p = 0; p < 66; ++p) {
    int m0, m1; float wy0, wy1;
    if ((p & 1) == 0) { m0 = (p >> 1) - 1; wy0 = 0.75f; m1 = p >> 1;       wy1 = 0.25f; }
    else              { m0 = (p - 3) >> 1; wy0 = 0.25f; m1 = (p - 1) >> 1; wy1 = 0.75f; }
    bool vm0 = (unsigned)m0 < 32u, vm1 = (unsigned)m1 < 32u;
    #pragma unroll 1
    for (int idx = t; idx < 528; idx += 256) {
      int x = idx >> 3, e = idx & 7;
      int n0, n1; float wx0, wx1;
      if ((x & 1) == 0) { n0 = (x >> 1) - 1; wx0 = 0.75f; n1 = x >> 1;       wx1 = 0.25f; }
      else              { n0 = (x - 3) >> 1; wx0 = 0.25f; n1 = (x - 1) >> 1; wx1 = 0.75f; }
      bool vn0 = (unsigned)n0 < 32u, vn1 = (unsigned)n1 < 32u;
      float a = 0.f;
      if (vm0 & vn0) a += wy0 * wx0 * base[((m0 * 32 + n0) << 9) + e];
      if (vm0 & vn1) a += wy0 * wx1 * base[((m0 * 32 + n1) << 9) + e];
      if (vm1 & vn0) a += wy1 * wx0 * base[((m1 * 32 + n0) << 9) + e];
      if (vm1 & vn1) a += wy1 * wx1 * base[((m1 * 32 + n1) << 9) + e];
      ob[(p * 66 + x) * 8 + e] = f2bf(a);
    }
  }
}

// ---------------------------------------------------------------------------
// 5) 256x256-tile MFMA conv (FROZEN from round 12 — green, 159us).
//    8 waves, BK=64, double-buffered LDS (128 KB), global_load_lds 2 tiles
//    ahead, counted vmcnt(8). K-planar global layouts; K-major LDS.
// ---------------------------------------------------------------------------
extern __shared__ u16 dynLds[];

template <int EPI>
__global__ __launch_bounds__(512, 2)
void conv8(const u16* __restrict__ xin,   // [b][64][66][66][8] bf16 K-planar
           const u16* __restrict__ wg,    // [b][9][64][512][8] bf16
           const float* __restrict__ noise,  // [64*64]
           const float* __restrict__ nsp,    // scalar
           const float* __restrict__ bias,   // [512]
           u16* __restrict__ hpOut,          // EPI=0 dest (K-planar, ring +1)
           float* __restrict__ hOut)         // EPI=1 dest
{
  // XCD-chunked bijective swizzle: 256 blocks = 8 xcd * 32
  int blk = (blockIdx.x & 7) * 32 + (blockIdx.x >> 3);
  int b  = blk >> 5;            // 8
  int ot = (blk >> 4) & 1;      // 2  (256-o tile)
  int pt = blk & 15;            // 16 (256-px tile = 4 output rows)
  int o0 = ot << 8;
  int y0 = pt << 2;

  int t = threadIdx.x;          // 0..511
  int w = t >> 6;               // wave 0..7
  int lane = t & 63;
  int gq = lane >> 4, r = lane & 15;
  int wm = w >> 2;              // A-half (0..1): 128 rows of A
  int wn = w & 3;               // B-quarter (0..3): 64 rows of B

  // K-major LDS: each matrix buffer = 8 j * 256 rows * 8 u16 = 16384 u16
  u16* Wb0 = dynLds;
  u16* Wb1 = dynLds + 16384;
  u16* Xb0 = dynLds + 32768;
  u16* Xb1 = dynLds + 49152;

  f32x4 acc[8][4];
  #pragma unroll
  for (int i = 0; i < 8; ++i)
    #pragma unroll
    for (int j = 0; j < 4; ++j) acc[i][j] = (f32x4){0.f, 0.f, 0.f, 0.f};

  const u16* wbB = wg + (size_t)b * 2359296;               // 9*64*512*8
  const u16* xbB = xin + (size_t)b * 2230272;              // 64*66*66*8

  // stage tile -> buffer pb: wave w stages k-chunk j=w; call q stages rows q*64+lane.
  auto STAGE = [&](int tile, int pb) {
    int tap = tile >> 3;
    int ck  = tile & 7;                   // 64-ch block -> kq_global = ck*8 + w
    int dy = (tap * 171) >> 9;            // tap/3
    int dx = tap - dy * 3;
    u16* dW = (pb ? Wb1 : Wb0) + w * 2048;
    u16* dX = (pb ? Xb1 : Xb0) + w * 2048;
    const u16* wsrc = wbB + ((size_t)(tap * 64 + ck * 8 + w)) * 4096 + (size_t)o0 * 8;
    const u16* xsrc = xbB + ((size_t)(ck * 8 + w) * 66) * 66 * 8;
    #pragma unroll
    for (int q = 0; q < 4; ++q) {
      int row = q * 64 + lane;
      gload16(wsrc + (size_t)row * 8, dW + q * 512);
      int yy = y0 + q + dy;
      int xx = lane + dx;
      gload16(xsrc + (((size_t)yy * 66) + xx) * 8, dX + q * 512);
    }
  };

  // compute one K-tile from buffer pb (granule (j,row) at j*2048 + row*8)
  auto TILE = [&](int pb) {
    const u16* Wp = pb ? Wb1 : Wb0;
    const u16* Xp = pb ? Xb1 : Xb0;
    const u16* A = (EPI == 0) ? Xp : Wp;
    const u16* B = (EPI == 0) ? Wp : Xp;
    bf16x8 bfr[4][2];
    #pragma unroll
    for (int fb = 0; fb < 4; ++fb)
      #pragma unroll
      for (int kk = 0; kk < 2; ++kk)
        bfr[fb][kk] = *(const bf16x8*)&B[((kk * 4 + gq) << 11) + ((wn * 64 + fb * 16 + r) << 3)];
    __builtin_amdgcn_s_setprio(1);
    #pragma unroll
    for (int fa = 0; fa < 8; ++fa) {
      int rowA = (wm * 128 + fa * 16 + r) << 3;
      bf16x8 a0 = *(const bf16x8*)&A[(gq << 11) + rowA];
      bf16x8 a1 = *(const bf16x8*)&A[((4 + gq) << 11) + rowA];
      #pragma unroll
      for (int fb = 0; fb < 4; ++fb) {
        acc[fa][fb] = __builtin_amdgcn_mfma_f32_16x16x32_bf16(a0, bfr[fb][0], acc[fa][fb], 0, 0, 0);
        acc[fa][fb] = __builtin_amdgcn_mfma_f32_16x16x32_bf16(a1, bfr[fb][1], acc[fa][fb], 0, 0, 0);
      }
    }
    __builtin_amdgcn_s_setprio(0);
  };

  // prologue: stage tiles 0 and 1
  STAGE(0, 0);
  STAGE(1, 1);
  asm volatile("s_waitcnt vmcnt(8)" ::: "memory");   // tile 0 landed (mine)
  __builtin_amdgcn_sched_barrier(0);
  __builtin_amdgcn_s_barrier();                      // everyone's tile 0 landed
  __builtin_amdgcn_sched_barrier(0);

  int p = 0;
  #pragma unroll 1
  for (int tl = 0; tl < 72; ++tl) {
    TILE(p);
    __builtin_amdgcn_sched_barrier(0);
    __builtin_amdgcn_s_barrier();                    // all waves done reading buf[p]
    __builtin_amdgcn_sched_barrier(0);
    if (tl < 70) {
      STAGE(tl + 2, p);                              // overwrite buf[p] with tile t+2
      asm volatile("s_waitcnt vmcnt(8)" ::: "memory"); // tile t+1 landed (mine)
    } else if (tl == 70) {
      asm volatile("s_waitcnt vmcnt(0)" ::: "memory"); // drain tile 71
    }
    __builtin_amdgcn_sched_barrier(0);
    __builtin_amdgcn_s_barrier();                    // everyone's tile t+1 landed
    __builtin_amdgcn_sched_barrier(0);
    p ^= 1;
  }
  __builtin_amdgcn_sched_barrier(0);

  float ns = nsp[0];
  // C/D map: col = lane&15 (B-index), row = (lane>>4)*4 + v (A-index)
  if constexpr (EPI == 0) {
    // A = pixels: px = wm*128 + fa*16 + gq*4+v ; B = weights: oo = o0+wn*64+fb*16+r
    #pragma unroll
    for (int fa = 0; fa < 8; ++fa) {
      #pragma unroll
      for (int fb = 0; fb < 4; ++fb) {
        int oo = o0 + wn * 64 + fb * 16 + r;
        float bo = bias[oo];
        #pragma unroll
        for (int v = 0; v < 4; ++v) {
          int px = wm * 128 + fa * 16 + gq * 4 + v;
          int pg = (pt << 8) + px;
          int y = pg >> 6, x2 = pg & 63;
          float val = acc[fa][fb][v] + noise[pg] * ns + bo;
          val = (val >= 0.f ? val : 0.2f * val) * LRELU_G;
          val = fminf(fmaxf(val, -256.f), 256.f);
          hpOut[((((size_t)b * 64 + (oo >> 3)) * 66 + (y + 1)) * 66 + (x2 + 1)) * 8 + (oo & 7)] = f2bf(val);
        }
      }
    }
  } else {
    // A = weights: oo = o0 + wm*128 + fa*16 + gq*4+v ; B = pixels: px = wn*64+fb*16+r
    #pragma unroll
    for (int fa = 0; fa < 8; ++fa) {
      #pragma unroll
      for (int fb = 0; fb < 4; ++fb) {
        int px = wn * 64 + fb * 16 + r;
        int pg = (pt << 8) + px;
        float nv = noise[pg] * ns;
        #pragma unroll
        for (int v = 0; v < 4; ++v) {
          int oo = o0 + wm * 128 + fa * 16 + gq * 4 + v;
          float val = acc[fa][fb][v] + nv + bias[oo];
          val = (val >= 0.f ? val : 0.2f * val) * LRELU_G;
          val = fminf(fmaxf(val, -256.f), 256.f);
          hOut[((size_t)(b * 512 + oo) << 12) + pg] = val;
        }
      }
    }
  }
}

// ---------------------------------------------------------------------------
// 6) toRGB + img skip
// ---------------------------------------------------------------------------
__global__ __launch_bounds__(256)
void torgb_kernel(const float* __restrict__ h, const float* __restrict__ s_all,
                  const float* __restrict__ wt, const float* __restrict__ bt,
                  const float* __restrict__ img, float* __restrict__ out2)
{
  int b = blockIdx.x >> 4;
  int y = ((blockIdx.x & 15) << 2) + (threadIdx.x >> 6);
  int x = threadIdx.x & 63;
  __shared__ float stw[3][512];
  const float* st = s_all + 2 * 4096 + b * 512;
  for (int i = threadIdx.x; i < 512; i += 256) {
    float s = st[i];
    stw[0][i] = s * wt[i];
    stw[1][i] = s * wt[512 + i];
    stw[2][i] = s * wt[1024 + i];
  }
  __syncthreads();
  const float* hp = h + ((size_t)b * 512 << 12) + (y << 6) + x;
  float a0 = 0.f, a1 = 0.f, a2 = 0.f;
  #pragma unroll 8
  for (int i = 0; i < 512; ++i) {
    float v = hp[(size_t)i << 12];
    a0 += v * stw[0][i]; a1 += v * stw[1][i]; a2 += v * stw[2][i];
  }
  float accs[3] = {a0, a1, a2};
  int my0, my1; float wy0, wy1;
  if ((y & 1) == 0) { my0 = (y >> 1) - 1; wy0 = 0.25f; my1 = y >> 1;       wy1 = 0.75f; }
  else              { my0 = y >> 1;       wy0 = 0.75f; my1 = (y >> 1) + 1; wy1 = 0.25f; }
  int mx0, mx1; float wx0, wx1;
  if ((x & 1) == 0) { mx0 = (x >> 1) - 1; wx0 = 0.25f; mx1 = x >> 1;       wx1 = 0.75f; }
  else              { mx0 = x >> 1;       wx0 = 0.75f; mx1 = (x >> 1) + 1; wx1 = 0.25f; }
  bool vy0 = (unsigned)my0 < 32u, vy1 = (unsigned)my1 < 32u;
  bool vx0 = (unsigned)mx0 < 32u, vx1 = (unsigned)mx1 < 32u;
  #pragma unroll
  for (int o = 0; o < 3; ++o) {
    float yv = fminf(fmaxf(accs[o] + bt[o], -256.f), 256.f);
    const float* ib = img + ((size_t)(b * 3 + o) << 10);
    float iu = 0.f;
    if (vy0 & vx0) iu += wy0 * wx0 * ib[(my0 << 5) + mx0];
    if (vy0 & vx1) iu += wy0 * wx1 * ib[(my0 << 5) + mx1];
    if (vy1 & vx0) iu += wy1 * wx0 * ib[(my1 << 5) + mx0];
    if (vy1 & vx1) iu += wy1 * wx1 * ib[(my1 << 5) + mx1];
    out2[((size_t)(b * 3 + o) << 12) + (y << 6) + x] = iu + yv;
  }
}

// ---------------------------------------------------------------------------
extern "C" void kernel_launch(void* const* d_in, const int* in_sizes, int n_in,
                              void* d_out, int out_size, void* d_ws, size_t ws_size,
                              hipStream_t stream) {
  (void)in_sizes; (void)n_in; (void)out_size; (void)ws_size;
  const float* x   = (const float*)d_in[0];
  const float* img = (const float*)d_in[1];
  const float* ws_ = (const float*)d_in[2];
  const float* a0w = (const float*)d_in[3];
  const float* a0b = (const float*)d_in[4];
  const float* w0  = (const float*)d_in[5];
  const float* b0  = (const float*)d_in[6];
  const float* ns0 = (const float*)d_in[7];
  const float* nc0 = (const float*)d_in[8];
  const float* a1w = (const float*)d_in[9];
  const float* a1b = (const float*)d_in[10];
  const float* w1  = (const float*)d_in[11];
  const float* b1  = (const float*)d_in[12];
  const float* ns1 = (const float*)d_in[13];
  const float* nc1 = (const float*)d_in[14];
  const float* atw = (const float*)d_in[15];
  const float* atb = (const float*)d_in[16];
  const float* wt  = (const float*)d_in[17];
  const float* bt  = (const float*)d_in[18];

  // workspace carve (~147 MB), all offsets 16B-aligned
  char* wsp = (char*)d_ws;
  float* s_all = (float*)wsp;                                   //      49,152 B
  u16* wg0 = (u16*)(wsp + 49152);                               //  37,748,736 B
  u16* wg1 = (u16*)(wsp + 49152 + 37748736ull);                 //  37,748,736 B
  u16* xb  = (u16*)(wsp + 49152 + 2ull * 37748736);             //  35,684,352 B
  u16* hp  = (u16*)(wsp + 49152 + 2ull * 37748736 + 35684352);  //  35,684,352 B
  float* d0 = (float*)(wsp + 49152 + 2ull * 37748736 + 2ull * 35684352);        // 16,384 B
  float* d1 = (float*)(wsp + 49152 + 2ull * 37748736 + 2ull * 35684352 + 16384);// 16,384 B
  float* xtf = (float*)hp;   // xt f32 aliases hp; dead before memset

  float* h_out = (float*)d_out;
  float* out2  = (float*)d_out + 16777216;

  // allow 128 KB dynamic LDS for the conv kernels (idempotent)
  hipFuncSetAttribute((const void*)conv8<0>,
                      hipFuncAttributeMaxDynamicSharedMemorySize, 131072);
  hipFuncSetAttribute((const void*)conv8<1>,
                      hipFuncAttributeMaxDynamicSharedMemorySize, 131072);

  style_kernel<<<3072, 256, 0, stream>>>(ws_, a0w, a0b, a1w, a1b, atw, atb, s_all);
  demod_kernel<<<4096, 256, 0, stream>>>(w0, s_all, d0);
  demod_kernel<<<4096, 256, 0, stream>>>(w1, s_all + 4096, d1);
  wpack_kernel<1><<<512, 256, 0, stream>>>(w0, s_all, d0, wg0);         // conv0: flipped
  wpack_kernel<0><<<512, 256, 0, stream>>>(w1, s_all + 4096, d1, wg1);  // conv1
  transpose_x<<<256, 256, 0, stream>>>(x, xtf);
  upblur_kernel<<<512, 256, 0, stream>>>(xtf, xb);
  hipMemsetAsync(hp, 0, 35684352, stream);  // zero padded ring for conv1 input (xtf now dead)
  conv8<0><<<256, 512, 131072, stream>>>(xb, wg0, nc0, ns0, b0, hp, nullptr);
  conv8<1><<<256, 512, 131072, stream>>>(hp, wg1, nc1, ns1, b1, nullptr, h_out);
  torgb_kernel<<<128, 256, 0, stream>>>(h_out, s_all, wt, bt, img, out2);
}

// Round 15
// 381.412 us; speedup vs baseline: 1.4074x; 1.4074x over previous
//
#include <hip/hip_runtime.h>
#include <stdint.h>

typedef unsigned short u16;
typedef unsigned int   u32;

#define DEVINL __device__ __forceinline__

typedef __bf16 bf16x8 __attribute__((ext_vector_type(8)));
typedef float  f32x4  __attribute__((ext_vector_type(4)));
typedef unsigned short u16x8 __attribute__((ext_vector_type(8)));

#define RSQRT512 0.044194173824159216f
#define LRELU_G  1.4142135623730951f

DEVINL u16 f2bf(float f) {           // RNE float->bf16 bits
  union { float f; u32 u; } v; v.f = f;
  u32 r = v.u + 0x7fffu + ((v.u >> 16) & 1u);
  return (u16)(r >> 16);
}
DEVINL float bf2f(u16 b) {
  union { u32 u; float f; } v; v.u = ((u32)b) << 16;
  return v.f;
}

#define AS1 __attribute__((address_space(1)))
#define AS3 __attribute__((address_space(3)))
// async global->LDS, 16B per lane; LDS dest = wave-uniform base + lane*16
DEVINL void gload16(const void* g, void* l) {
  __builtin_amdgcn_global_load_lds((AS1 const u32*)(uintptr_t)g,
                                   (AS3 u32*)(u32)(uintptr_t)l, 16, 0, 0);
}

// ---------------------------------------------------------------------------
// 1) styles
// ---------------------------------------------------------------------------
__global__ __launch_bounds__(256)
void style_kernel(const float* __restrict__ wsin,
                  const float* __restrict__ a0w, const float* __restrict__ a0b,
                  const float* __restrict__ a1w, const float* __restrict__ a1b,
                  const float* __restrict__ atw, const float* __restrict__ atb,
                  float* __restrict__ s_all)
{
  int wid = threadIdx.x >> 6, lane = threadIdx.x & 63;
  int idx = blockIdx.x * 4 + wid;            // [0, 3*8*512)
  int j = idx >> 12;
  int b = (idx >> 9) & 7;
  int o = idx & 511;
  const float* A  = (j == 0) ? a0w : ((j == 1) ? a1w : atw);
  const float* Ab = (j == 0) ? a0b : ((j == 1) ? a1b : atb);
  const float* wv = wsin + (b * 3 + j) * 512;
  float p = 0.f;
  #pragma unroll
  for (int m = 0; m < 512; m += 64) p += wv[m + lane] * A[(size_t)o * 512 + m + lane];
  #pragma unroll
  for (int s = 32; s; s >>= 1) p += __shfl_xor(p, s, 64);
  if (lane == 0) {
    float v = p * RSQRT512 + Ab[o];
    if (j == 2) v *= RSQRT512;
    s_all[idx] = v;
  }
}

// ---------------------------------------------------------------------------
// 2a) demod: d[b][o] = rsqrt(sum_{i,k} (w*s)^2 + 1e-8)
// ---------------------------------------------------------------------------
__global__ __launch_bounds__(256)
void demod_kernel(const float* __restrict__ w, const float* __restrict__ s_j,
                  float* __restrict__ dOut)
{
  int b = blockIdx.x >> 9;
  int o = blockIdx.x & 511;
  __shared__ float s_sh[512];
  __shared__ float red[4];
  int t = threadIdx.x;
  s_sh[t]       = s_j[b * 512 + t];
  s_sh[t + 256] = s_j[b * 512 + t + 256];
  __syncthreads();
  float ssq = 0.f;
  #pragma unroll
  for (int hh = 0; hh < 2; ++hh) {
    int i = t + hh * 256;
    float si = s_sh[i];
    const float* wp = w + ((size_t)o * 512 + i) * 9;
    #pragma unroll
    for (int k = 0; k < 9; ++k) { float v = wp[k] * si; ssq += v * v; }
  }
  #pragma unroll
  for (int s = 32; s; s >>= 1) ssq += __shfl_xor(ssq, s, 64);
  if ((t & 63) == 0) red[t >> 6] = ssq;
  __syncthreads();
  if (t == 0) {
    float d = red[0] + red[1] + red[2] + red[3];
    dOut[b * 512 + o] = 1.0f / sqrtf(d + 1e-8f);
  }
}

// ---------------------------------------------------------------------------
// 2b) wpack: emit wg2[b][tapOut][kq][o][8] bf16, COALESCED writes (1KB/wave).
//    FLIP: source tap ksrc = 8 - tapOut
// ---------------------------------------------------------------------------
template <int FLIP>
__global__ __launch_bounds__(256)
void wpack_kernel(const float* __restrict__ w, const float* __restrict__ s_j,
                  const float* __restrict__ dIn, u16* __restrict__ wg)
{
  int b = blockIdx.x >> 6;
  int kq = blockIdx.x & 63;
  float sv[8];
  #pragma unroll
  for (int e = 0; e < 8; ++e) sv[e] = s_j[b * 512 + kq * 8 + e];
  int t = threadIdx.x;
  #pragma unroll 1
  for (int rep = 0; rep < 2; ++rep) {
    int o = rep * 256 + t;
    float d = dIn[b * 512 + o];
    const float* wp = w + ((size_t)o * 512 + kq * 8) * 9;   // 72 consecutive f32
    float wv[72];
    #pragma unroll
    for (int j = 0; j < 72; ++j) wv[j] = wp[j];
    #pragma unroll
    for (int tapOut = 0; tapOut < 9; ++tapOut) {
      int ksrc = FLIP ? (8 - tapOut) : tapOut;
      u16x8 g;
      #pragma unroll
      for (int e = 0; e < 8; ++e) g[e] = f2bf(wv[e * 9 + ksrc] * sv[e] * d);
      *(u16x8*)&wg[((((size_t)(b * 9 + tapOut)) * 64 + kq) * 512 + o) * 8] = g;
    }
  }
}

// ---------------------------------------------------------------------------
// 3) fused transpose+blur-upsample: x NCHW f32 -> xb2 K-planar bf16
//    block=(b,c8): stage 8 channel planes (32KB, coalesced 4KB runs) in LDS,
//    compute 66x66 outputs, COALESCED 16B granule writes.
// ---------------------------------------------------------------------------
__global__ __launch_bounds__(256)
void upblur_kernel(const float* __restrict__ x, u16* __restrict__ xb)
{
  int b = blockIdx.x >> 6, c8 = blockIdx.x & 63;
  __shared__ float slab[8192];                 // [e][32][32]
  int t = threadIdx.x;
  const float* sp = x + (((size_t)(b * 512 + c8 * 8)) << 10);
  #pragma unroll
  for (int i = 0; i < 32; ++i) slab[t + i * 256] = sp[t + i * 256];
  __syncthreads();
  u16* ob = xb + ((size_t)(b * 64 + c8)) * 34848;   // 66*66*8
  #pragma unroll 1
  for (int idx = t; idx < 4356; idx += 256) {
    int p = idx / 66;
    int q = idx - p * 66;
    int m0, m1; float wy0, wy1;
    if ((p & 1) == 0) { m0 = (p >> 1) - 1; wy0 = 0.75f; m1 = p >> 1;       wy1 = 0.25f; }
    else              { m0 = (p - 3) >> 1; wy0 = 0.25f; m1 = (p - 1) >> 1; wy1 = 0.75f; }
    int n0, n1; float wx0, wx1;
    if ((q & 1) == 0) { n0 = (q >> 1) - 1; wx0 = 0.75f; n1 = q >> 1;       wx1 = 0.25f; }
    else              { n0 = (q - 3) >> 1; wx0 = 0.25f; n1 = (q - 1) >> 1; wx1 = 0.75f; }
    bool vm0 = (unsigned)m0 < 32u, vm1 = (unsigned)m1 < 32u;
    bool vn0 = (unsigned)n0 < 32u, vn1 = (unsigned)n1 < 32u;
    float w00 = (vm0 & vn0) ? wy0 * wx0 : 0.f;
    float w01 = (vm0 & vn1) ? wy0 * wx1 : 0.f;
    float w10 = (vm1 & vn0) ? wy1 * wx0 : 0.f;
    float w11 = (vm1 & vn1) ? wy1 * wx1 : 0.f;
    int i00 = ((m0 & 31) << 5) + (n0 & 31);   // clamped; weight=0 when invalid
    int i01 = ((m0 & 31) << 5) + (n1 & 31);
    int i10 = ((m1 & 31) << 5) + (n0 & 31);
    int i11 = ((m1 & 31) << 5) + (n1 & 31);
    u16x8 g;
    #pragma unroll
    for (int e = 0; e < 8; ++e) {
      const float* se = slab + (e << 10);
      float a = w00 * se[i00] + w01 * se[i01] + w10 * se[i10] + w11 * se[i11];
      g[e] = f2bf(a);
    }
    *(u16x8*)&ob[idx * 8] = g;
  }
}

// ---------------------------------------------------------------------------
// 5) 256x256-tile MFMA conv (FROZEN — green, 159us/dispatch).
// ---------------------------------------------------------------------------
extern __shared__ u16 dynLds[];

template <int EPI>
__global__ __launch_bounds__(512, 2)
void conv8(const u16* __restrict__ xin,   // [b][64][66][66][8] bf16 K-planar
           const u16* __restrict__ wg,    // [b][9][64][512][8] bf16
           const float* __restrict__ noise,  // [64*64]
           const float* __restrict__ nsp,    // scalar
           const float* __restrict__ bias,   // [512]
           u16* __restrict__ hpOut,          // EPI=0 dest (K-planar, ring +1)
           float* __restrict__ hOut)         // EPI=1 dest
{
  // XCD-chunked bijective swizzle: 256 blocks = 8 xcd * 32
  int blk = (blockIdx.x & 7) * 32 + (blockIdx.x >> 3);
  int b  = blk >> 5;            // 8
  int ot = (blk >> 4) & 1;      // 2  (256-o tile)
  int pt = blk & 15;            // 16 (256-px tile = 4 output rows)
  int o0 = ot << 8;
  int y0 = pt << 2;

  int t = threadIdx.x;          // 0..511
  int w = t >> 6;               // wave 0..7
  int lane = t & 63;
  int gq = lane >> 4, r = lane & 15;
  int wm = w >> 2;              // A-half (0..1): 128 rows of A
  int wn = w & 3;               // B-quarter (0..3): 64 rows of B

  // K-major LDS: each matrix buffer = 8 j * 256 rows * 8 u16 = 16384 u16
  u16* Wb0 = dynLds;
  u16* Wb1 = dynLds + 16384;
  u16* Xb0 = dynLds + 32768;
  u16* Xb1 = dynLds + 49152;

  f32x4 acc[8][4];
  #pragma unroll
  for (int i = 0; i < 8; ++i)
    #pragma unroll
    for (int j = 0; j < 4; ++j) acc[i][j] = (f32x4){0.f, 0.f, 0.f, 0.f};

  const u16* wbB = wg + (size_t)b * 2359296;               // 9*64*512*8
  const u16* xbB = xin + (size_t)b * 2230272;              // 64*66*66*8

  // stage tile -> buffer pb: wave w stages k-chunk j=w; call q stages rows q*64+lane.
  auto STAGE = [&](int tile, int pb) {
    int tap = tile >> 3;
    int ck  = tile & 7;                   // 64-ch block -> kq_global = ck*8 + w
    int dy = (tap * 171) >> 9;            // tap/3
    int dx = tap - dy * 3;
    u16* dW = (pb ? Wb1 : Wb0) + w * 2048;
    u16* dX = (pb ? Xb1 : Xb0) + w * 2048;
    const u16* wsrc = wbB + ((size_t)(tap * 64 + ck * 8 + w)) * 4096 + (size_t)o0 * 8;
    const u16* xsrc = xbB + ((size_t)(ck * 8 + w) * 66) * 66 * 8;
    #pragma unroll
    for (int q = 0; q < 4; ++q) {
      int row = q * 64 + lane;
      gload16(wsrc + (size_t)row * 8, dW + q * 512);
      int yy = y0 + q + dy;
      int xx = lane + dx;
      gload16(xsrc + (((size_t)yy * 66) + xx) * 8, dX + q * 512);
    }
  };

  // compute one K-tile from buffer pb (granule (j,row) at j*2048 + row*8)
  auto TILE = [&](int pb) {
    const u16* Wp = pb ? Wb1 : Wb0;
    const u16* Xp = pb ? Xb1 : Xb0;
    const u16* A = (EPI == 0) ? Xp : Wp;
    const u16* B = (EPI == 0) ? Wp : Xp;
    bf16x8 bfr[4][2];
    #pragma unroll
    for (int fb = 0; fb < 4; ++fb)
      #pragma unroll
      for (int kk = 0; kk < 2; ++kk)
        bfr[fb][kk] = *(const bf16x8*)&B[((kk * 4 + gq) << 11) + ((wn * 64 + fb * 16 + r) << 3)];
    __builtin_amdgcn_s_setprio(1);
    #pragma unroll
    for (int fa = 0; fa < 8; ++fa) {
      int rowA = (wm * 128 + fa * 16 + r) << 3;
      bf16x8 a0 = *(const bf16x8*)&A[(gq << 11) + rowA];
      bf16x8 a1 = *(const bf16x8*)&A[((4 + gq) << 11) + rowA];
      #pragma unroll
      for (int fb = 0; fb < 4; ++fb) {
        acc[fa][fb] = __builtin_amdgcn_mfma_f32_16x16x32_bf16(a0, bfr[fb][0], acc[fa][fb], 0, 0, 0);
        acc[fa][fb] = __builtin_amdgcn_mfma_f32_16x16x32_bf16(a1, bfr[fb][1], acc[fa][fb], 0, 0, 0);
      }
    }
    __builtin_amdgcn_s_setprio(0);
  };

  // prologue: stage tiles 0 and 1
  STAGE(0, 0);
  STAGE(1, 1);
  asm volatile("s_waitcnt vmcnt(8)" ::: "memory");   // tile 0 landed (mine)
  __builtin_amdgcn_sched_barrier(0);
  __builtin_amdgcn_s_barrier();                      // everyone's tile 0 landed
  __builtin_amdgcn_sched_barrier(0);

  int p = 0;
  #pragma unroll 1
  for (int tl = 0; tl < 72; ++tl) {
    TILE(p);
    __builtin_amdgcn_sched_barrier(0);
    __builtin_amdgcn_s_barrier();                    // all waves done reading buf[p]
    __builtin_amdgcn_sched_barrier(0);
    if (tl < 70) {
      STAGE(tl + 2, p);                              // overwrite buf[p] with tile t+2
      asm volatile("s_waitcnt vmcnt(8)" ::: "memory"); // tile t+1 landed (mine)
    } else if (tl == 70) {
      asm volatile("s_waitcnt vmcnt(0)" ::: "memory"); // drain tile 71
    }
    __builtin_amdgcn_sched_barrier(0);
    __builtin_amdgcn_s_barrier();                    // everyone's tile t+1 landed
    __builtin_amdgcn_sched_barrier(0);
    p ^= 1;
  }
  __builtin_amdgcn_sched_barrier(0);

  float ns = nsp[0];
  // C/D map: col = lane&15 (B-index), row = (lane>>4)*4 + v (A-index)
  if constexpr (EPI == 0) {
    // A = pixels: px = wm*128 + fa*16 + gq*4+v ; B = weights: oo = o0+wn*64+fb*16+r
    #pragma unroll
    for (int fa = 0; fa < 8; ++fa) {
      #pragma unroll
      for (int fb = 0; fb < 4; ++fb) {
        int oo = o0 + wn * 64 + fb * 16 + r;
        float bo = bias[oo];
        #pragma unroll
        for (int v = 0; v < 4; ++v) {
          int px = wm * 128 + fa * 16 + gq * 4 + v;
          int pg = (pt << 8) + px;
          int y = pg >> 6, x2 = pg & 63;
          float val = acc[fa][fb][v] + noise[pg] * ns + bo;
          val = (val >= 0.f ? val : 0.2f * val) * LRELU_G;
          val = fminf(fmaxf(val, -256.f), 256.f);
          hpOut[((((size_t)b * 64 + (oo >> 3)) * 66 + (y + 1)) * 66 + (x2 + 1)) * 8 + (oo & 7)] = f2bf(val);
        }
      }
    }
  } else {
    // A = weights: oo = o0 + wm*128 + fa*16 + gq*4+v ; B = pixels: px = wn*64+fb*16+r
    #pragma unroll
    for (int fa = 0; fa < 8; ++fa) {
      #pragma unroll
      for (int fb = 0; fb < 4; ++fb) {
        int px = wn * 64 + fb * 16 + r;
        int pg = (pt << 8) + px;
        float nv = noise[pg] * ns;
        #pragma unroll
        for (int v = 0; v < 4; ++v) {
          int oo = o0 + wm * 128 + fa * 16 + gq * 4 + v;
          float val = acc[fa][fb][v] + nv + bias[oo];
          val = (val >= 0.f ? val : 0.2f * val) * LRELU_G;
          val = fminf(fmaxf(val, -256.f), 256.f);
          hOut[((size_t)(b * 512 + oo) << 12) + pg] = val;
        }
      }
    }
  }
}

// ---------------------------------------------------------------------------
// 6) toRGB + img skip
// ---------------------------------------------------------------------------
__global__ __launch_bounds__(256)
void torgb_kernel(const float* __restrict__ h, const float* __restrict__ s_all,
                  const float* __restrict__ wt, const float* __restrict__ bt,
                  const float* __restrict__ img, float* __restrict__ out2)
{
  int b = blockIdx.x >> 4;
  int y = ((blockIdx.x & 15) << 2) + (threadIdx.x >> 6);
  int x = threadIdx.x & 63;
  __shared__ float stw[3][512];
  const float* st = s_all + 2 * 4096 + b * 512;
  for (int i = threadIdx.x; i < 512; i += 256) {
    float s = st[i];
    stw[0][i] = s * wt[i];
    stw[1][i] = s * wt[512 + i];
    stw[2][i] = s * wt[1024 + i];
  }
  __syncthreads();
  const float* hp = h + ((size_t)b * 512 << 12) + (y << 6) + x;
  float a0 = 0.f, a1 = 0.f, a2 = 0.f;
  #pragma unroll 8
  for (int i = 0; i < 512; ++i) {
    float v = hp[(size_t)i << 12];
    a0 += v * stw[0][i]; a1 += v * stw[1][i]; a2 += v * stw[2][i];
  }
  float accs[3] = {a0, a1, a2};
  int my0, my1; float wy0, wy1;
  if ((y & 1) == 0) { my0 = (y >> 1) - 1; wy0 = 0.25f; my1 = y >> 1;       wy1 = 0.75f; }
  else              { my0 = y >> 1;       wy0 = 0.75f; my1 = (y >> 1) + 1; wy1 = 0.25f; }
  int mx0, mx1; float wx0, wx1;
  if ((x & 1) == 0) { mx0 = (x >> 1) - 1; wx0 = 0.25f; mx1 = x >> 1;       wx1 = 0.75f; }
  else              { mx0 = x >> 1;       wx0 = 0.75f; mx1 = (x >> 1) + 1; wx1 = 0.25f; }
  bool vy0 = (unsigned)my0 < 32u, vy1 = (unsigned)my1 < 32u;
  bool vx0 = (unsigned)mx0 < 32u, vx1 = (unsigned)mx1 < 32u;
  #pragma unroll
  for (int o = 0; o < 3; ++o) {
    float yv = fminf(fmaxf(accs[o] + bt[o], -256.f), 256.f);
    const float* ib = img + ((size_t)(b * 3 + o) << 10);
    float iu = 0.f;
    if (vy0 & vx0) iu += wy0 * wx0 * ib[(my0 << 5) + mx0];
    if (vy0 & vx1) iu += wy0 * wx1 * ib[(my0 << 5) + mx1];
    if (vy1 & vx0) iu += wy1 * wx0 * ib[(my1 << 5) + mx0];
    if (vy1 & vx1) iu += wy1 * wx1 * ib[(my1 << 5) + mx1];
    out2[((size_t)(b * 3 + o) << 12) + (y << 6) + x] = iu + yv;
  }
}

// ---------------------------------------------------------------------------
extern "C" void kernel_launch(void* const* d_in, const int* in_sizes, int n_in,
                              void* d_out, int out_size, void* d_ws, size_t ws_size,
                              hipStream_t stream) {
  (void)in_sizes; (void)n_in; (void)out_size; (void)ws_size;
  const float* x   = (const float*)d_in[0];
  const float* img = (const float*)d_in[1];
  const float* ws_ = (const float*)d_in[2];
  const float* a0w = (const float*)d_in[3];
  const float* a0b = (const float*)d_in[4];
  const float* w0  = (const float*)d_in[5];
  const float* b0  = (const float*)d_in[6];
  const float* ns0 = (const float*)d_in[7];
  const float* nc0 = (const float*)d_in[8];
  const float* a1w = (const float*)d_in[9];
  const float* a1b = (const float*)d_in[10];
  const float* w1  = (const float*)d_in[11];
  const float* b1  = (const float*)d_in[12];
  const float* ns1 = (const float*)d_in[13];
  const float* nc1 = (const float*)d_in[14];
  const float* atw = (const float*)d_in[15];
  const float* atb = (const float*)d_in[16];
  const float* wt  = (const float*)d_in[17];
  const float* bt  = (const float*)d_in[18];

  // workspace carve (~147 MB), all offsets 16B-aligned
  char* wsp = (char*)d_ws;
  float* s_all = (float*)wsp;                                   //      49,152 B
  u16* wg0 = (u16*)(wsp + 49152);                               //  37,748,736 B
  u16* wg1 = (u16*)(wsp + 49152 + 37748736ull);                 //  37,748,736 B
  u16* xb  = (u16*)(wsp + 49152 + 2ull * 37748736);             //  35,684,352 B
  u16* hp  = (u16*)(wsp + 49152 + 2ull * 37748736 + 35684352);  //  35,684,352 B
  float* d0 = (float*)(wsp + 49152 + 2ull * 37748736 + 2ull * 35684352);        // 16,384 B
  float* d1 = (float*)(wsp + 49152 + 2ull * 37748736 + 2ull * 35684352 + 16384);// 16,384 B

  float* h_out = (float*)d_out;
  float* out2  = (float*)d_out + 16777216;

  // allow 128 KB dynamic LDS for the conv kernels (idempotent)
  (void)hipFuncSetAttribute((const void*)conv8<0>,
                            hipFuncAttributeMaxDynamicSharedMemorySize, 131072);
  (void)hipFuncSetAttribute((const void*)conv8<1>,
                            hipFuncAttributeMaxDynamicSharedMemorySize, 131072);

  style_kernel<<<3072, 256, 0, stream>>>(ws_, a0w, a0b, a1w, a1b, atw, atb, s_all);
  demod_kernel<<<4096, 256, 0, stream>>>(w0, s_all, d0);
  demod_kernel<<<4096, 256, 0, stream>>>(w1, s_all + 4096, d1);
  wpack_kernel<1><<<512, 256, 0, stream>>>(w0, s_all, d0, wg0);         // conv0: flipped
  wpack_kernel<0><<<512, 256, 0, stream>>>(w1, s_all + 4096, d1, wg1);  // conv1
  upblur_kernel<<<512, 256, 0, stream>>>(x, xb);                        // fused transpose+upblur
  (void)hipMemsetAsync(hp, 0, 35684352, stream);  // zero padded ring for conv1 input
  conv8<0><<<256, 512, 131072, stream>>>(xb, wg0, nc0, ns0, b0, hp, nullptr);
  conv8<1><<<256, 512, 131072, stream>>>(hp, wg1, nc1, ns1, b1, nullptr, h_out);
  torgb_kernel<<<128, 256, 0, stream>>>(h_out, s_all, wt, bt, img, out2);
}